// Round 17
// baseline (185.406 us; speedup 1.0000x reference)
//
#include <hip/hip_runtime.h>

typedef unsigned short u16;
typedef unsigned int   u32;
typedef __attribute__((ext_vector_type(8))) short bf16x8;
typedef __attribute__((ext_vector_type(4))) float f32x4;

#define SEQ 2048
#define DIM 1024
#define NH  16
#define DH  64
#define NROW 4096

static __device__ __forceinline__ u16 f2bf(float f){
  u32 u; __builtin_memcpy(&u, &f, 4);
  u32 r = (u + 0x7fffu + ((u >> 16) & 1u)) >> 16;
  return (u16)r;
}
// round-half-up pack of two fp32 -> two bf16 in one u32 (low = a, high = b)
static __device__ __forceinline__ u32 pack2bf(float a, float b){
  u32 ua, ub; __builtin_memcpy(&ua, &a, 4); __builtin_memcpy(&ub, &b, 4);
  return ((ua + 0x8000u) >> 16) | ((ub + 0x8000u) & 0xFFFF0000u);
}
// single-instruction RNE pack (lo = a, hi = b)
static __device__ __forceinline__ u32 cvt_pk_bf16(float a, float b){
  u32 r;
  asm("v_cvt_pk_bf16_f32 %0, %1, %2" : "=v"(r) : "v"(a), "v"(b));
  return r;
}

#define GLD_LDS(gp, lp) \
  __builtin_amdgcn_global_load_lds( \
      (const __attribute__((address_space(1))) void*)(gp), \
      (__attribute__((address_space(3))) void*)(lp), 16, 0, 0)

// counted waitcnt with compiler memory fence (blocks ds_read/GLD motion across)
#define WAIT_VM(N) asm volatile("s_waitcnt vmcnt(" #N ")" ::: "memory")
#define CFENCE()   asm volatile("" ::: "memory")

// ---------------- RMSNorm: x[4096][1024] fp32 -> h bf16 ----------------
__global__ __launch_bounds__(256) void k_rmsnorm(const float* __restrict__ x,
                                                 const float* __restrict__ sc,
                                                 u16* __restrict__ h){
  int row = blockIdx.x, t = threadIdx.x;
  float4 v = ((const float4*)(x + (size_t)row * DIM))[t];
  float ss = v.x*v.x + v.y*v.y + v.z*v.z + v.w*v.w;
  #pragma unroll
  for (int d = 32; d; d >>= 1) ss += __shfl_down(ss, d, 64);
  __shared__ float red[4];
  if ((t & 63) == 0) red[t >> 6] = ss;
  __syncthreads();
  float tot = red[0] + red[1] + red[2] + red[3];
  float rms = rsqrtf(tot * (1.0f / DIM) + 1e-6f);
  float4 s4 = ((const float4*)sc)[t];
  u16 ov[4];
  ov[0] = f2bf(v.x * rms * s4.x);
  ov[1] = f2bf(v.y * rms * s4.y);
  ov[2] = f2bf(v.z * rms * s4.z);
  ov[3] = f2bf(v.w * rms * s4.w);
  ((uint2*)(h + (size_t)row * DIM))[t] = *(uint2*)ov;
}

// ------- Weight transpose: fp32 K-major [1024][1024] -> bf16 N-major [n][k] -------
__global__ __launch_bounds__(256) void k_wtrans(const float* __restrict__ in0,
                                                const float* __restrict__ in1,
                                                const float* __restrict__ in2,
                                                u16* __restrict__ outT){
  __shared__ u16 tile[64][68];
  int t = threadIdx.x;
  int c0 = blockIdx.x * 64;   // n
  int r0 = blockIdx.y * 64;   // k
  int z = blockIdx.z;
  const float* in = (z == 0) ? in0 : ((z == 1) ? in1 : in2);
  u16* out = outT + (size_t)z * (1u << 20);
  #pragma unroll
  for (int i = 0; i < 4; i++){
    int idx = t + 256 * i;
    int r = idx >> 4, c4 = (idx & 15) * 4;
    float4 v = *(const float4*)&in[(size_t)(r0 + r) * 1024 + c0 + c4];
    u16 pk[4] = {f2bf(v.x), f2bf(v.y), f2bf(v.z), f2bf(v.w)};
    *(uint2*)&tile[r][c4] = *(uint2*)pk;
  }
  __syncthreads();
  #pragma unroll
  for (int i = 0; i < 2; i++){
    int c = t + 256 * i;
    int n = c >> 3, koff = (c & 7) * 8;
    alignas(16) u16 vals[8];
    #pragma unroll
    for (int j = 0; j < 8; j++) vals[j] = tile[koff + j][n];
    *(uint4*)&out[(size_t)(c0 + n) * 1024 + r0 + koff] = *(uint4*)vals;
  }
}

// ---------------- QKV GEMM: 128x128, triple-buffered counted-vmcnt, T2 swizzle ----
// (R13 known-good, verbatim.)
__global__ __launch_bounds__(256) void k_gemm(const u16* __restrict__ A,
                                              const u16* __restrict__ B0,
                                              const u16* __restrict__ B1,
                                              const u16* __restrict__ B2,
                                              void* __restrict__ C0,
                                              void* __restrict__ C1,
                                              void* __restrict__ C2){
  __shared__ __align__(16) char smem[49152];      // 3-buf staging; reused for repack
  u16 (*Al)[128][32] = (u16 (*)[128][32])smem;
  u16 (*Bl)[128][32] = (u16 (*)[128][32])(smem + 24576);
  int t = threadIdx.x, lane = t & 63, w = t >> 6;
  int wm = w & 1, wn = w >> 1;
  int mrow = lane & 15, quad = lane >> 4;

  int id = blockIdx.x;
  int wg = (id & 7) * 96 + (id >> 3);   // 768 wgs, 96/XCD chunk
  int z = wg >> 8;
  int rem = wg & 255;
  int m0 = (rem >> 3) << 7;   // m-minor within XCD chunk
  int n0 = (rem & 7) << 7;
  const u16* Bt = (z == 0) ? B0 : ((z == 1) ? B1 : B2);

  int r0s = t >> 2;                      // staged row (i=0); i=1 -> +64
  int r1s = r0s + 64;
  int dst0 = (t & 3) * 8;                // LDS linear chunk (u16 units)
  int src0 = ((t & 3) ^ ((r0s & 3) ^ ((r0s >> 2) & 1))) * 8;   // swizzled global chunk

  const u16* Ap0 = &A [(size_t)(m0 + r0s) * 1024 + src0];
  const u16* Ap1 = &A [(size_t)(m0 + r1s) * 1024 + src0];
  const u16* Bp0 = &Bt[(size_t)(n0 + r0s) * 1024 + src0];
  const u16* Bp1 = &Bt[(size_t)(n0 + r1s) * 1024 + src0];

  int csw = (quad ^ ((mrow & 3) ^ ((mrow >> 2) & 1))) * 8;

  f32x4 acc[4][4];
  #pragma unroll
  for (int ms = 0; ms < 4; ms++)
    #pragma unroll
    for (int ns = 0; ns < 4; ns++) acc[ms][ns] = (f32x4){0.f, 0.f, 0.f, 0.f};

  GLD_LDS(Ap0,      &Al[0][r0s][dst0]);
  GLD_LDS(Ap1,      &Al[0][r1s][dst0]);
  GLD_LDS(Bp0,      &Bl[0][r0s][dst0]);
  GLD_LDS(Bp1,      &Bl[0][r1s][dst0]);
  CFENCE();
  GLD_LDS(Ap0 + 32, &Al[1][r0s][dst0]);
  GLD_LDS(Ap1 + 32, &Al[1][r1s][dst0]);
  GLD_LDS(Bp0 + 32, &Bl[1][r0s][dst0]);
  GLD_LDS(Bp1 + 32, &Bl[1][r1s][dst0]);

  int cur = 0, pf = 2;
  for (int kt = 0; kt < 32; kt++){
    if (kt < 31) WAIT_VM(4); else WAIT_VM(0);
    __builtin_amdgcn_s_barrier();
    CFENCE();
    if (kt < 30){
      int K2 = (kt + 2) * 32;
      GLD_LDS(Ap0 + K2, &Al[pf][r0s][dst0]);
      GLD_LDS(Ap1 + K2, &Al[pf][r1s][dst0]);
      GLD_LDS(Bp0 + K2, &Bl[pf][r0s][dst0]);
      GLD_LDS(Bp1 + K2, &Bl[pf][r1s][dst0]);
    }
    bf16x8 af[4], bfr[4];
    #pragma unroll
    for (int ms = 0; ms < 4; ms++)
      af[ms] = *(const bf16x8*)&Al[cur][wm * 64 + ms * 16 + mrow][csw];
    #pragma unroll
    for (int ns = 0; ns < 4; ns++)
      bfr[ns] = *(const bf16x8*)&Bl[cur][wn * 64 + ns * 16 + mrow][csw];
    #pragma unroll
    for (int ms = 0; ms < 4; ms++)
      #pragma unroll
      for (int ns = 0; ns < 4; ns++)
        acc[ms][ns] = __builtin_amdgcn_mfma_f32_16x16x32_bf16(af[ms], bfr[ns], acc[ms][ns], 0, 0, 0);
    cur = (cur == 2) ? 0 : cur + 1;
    pf  = (pf  == 2) ? 0 : pf  + 1;
  }

  float qscale = (z == 0) ? 0.180336880111112f : 1.0f;   // 0.125*log2e folded into Q

  __syncthreads();
  if (z == 2){
    #pragma unroll
    for (int ms = 0; ms < 4; ms++){
      #pragma unroll
      for (int ns = 0; ns < 4; ns++){
        int le = wn * 64 + ns * 16 + mrow;
        int ls = wm * 64 + ms * 16 + quad * 4;
        int ph = (ls >> 3) ^ (le & 7);
        uint2 pk = { pack2bf(acc[ms][ns][0], acc[ms][ns][1]),
                     pack2bf(acc[ms][ns][2], acc[ms][ns][3]) };
        *(uint2*)(smem + le * 256 + ph * 16 + (ls & 7) * 2) = pk;
      }
    }
    __syncthreads();
    int bidx = m0 >> 11, sl0 = m0 & 2047;
    u16* Cb = (u16*)C2;
    #pragma unroll
    for (int j = 0; j < 8; j++){
      int le = w * 32 + j * 4 + (lane >> 4);
      int c  = lane & 15;
      int ph = c ^ (le & 7);
      int hh2 = (n0 + le) >> 6, e = (n0 + le) & 63;
      uint4 v = *(uint4*)(smem + le * 256 + ph * 16);
      *(uint4*)&Cb[(size_t)((bidx * NH + hh2) * DH + e) * SEQ + sl0 + c * 8] = v;
    }
  } else {
    #pragma unroll
    for (int ms = 0; ms < 4; ms++){
      #pragma unroll
      for (int ns = 0; ns < 4; ns++){
        int ld  = wn * 64 + ns * 16 + mrow;
        int lsb = wm * 64 + ms * 16 + quad * 4;
        #pragma unroll
        for (int r = 0; r < 4; r++){
          int ls = lsb + r;
          int ph = (ld >> 3) ^ (ls & 7);
          *(u16*)(smem + ls * 256 + ph * 16 + (ld & 7) * 2) = f2bf(acc[ms][ns][r] * qscale);
        }
      }
    }
    __syncthreads();
    u16* Cb = (u16*)((z == 0) ? C0 : C1);
    #pragma unroll
    for (int j = 0; j < 8; j++){
      int row = w * 32 + j * 4 + (lane >> 4);
      int c   = lane & 15;
      int ph  = c ^ (row & 7);
      uint4 v = *(uint4*)(smem + row * 256 + ph * 16);
      *(uint4*)&Cb[(size_t)(m0 + row) * 1024 + n0 + c * 8] = v;
    }
  }
}

// ---------------- Out-proj GEMM: 128m x 64n tiles, grid 512 (R13 verbatim) --------
// R16 identified the 64x64/grid-1024 retile as a timing-sensitive racer
// (tripwire divergence, mechanism unexplained) — permanently reverted to this.
__global__ __launch_bounds__(256) void k_gemm_out(const u16* __restrict__ A,
                                                  const u16* __restrict__ Bt,
                                                  float* __restrict__ C,
                                                  const float* __restrict__ bias){
  __shared__ __align__(16) char smem[36864];      // A 24KB + B 12KB staging; repack 32KB
  u16 (*Al)[128][32] = (u16 (*)[128][32])smem;
  u16 (*Bl)[ 64][32] = (u16 (*)[ 64][32])(smem + 24576);
  int t = threadIdx.x, lane = t & 63, w = t >> 6;
  int wm = w & 1, wn = w >> 1;
  int mrow = lane & 15, quad = lane >> 4;

  int id = blockIdx.x;
  int wg = (id & 7) * 64 + (id >> 3);   // 512 wgs, 64/XCD chunk
  int m0 = (wg >> 4) << 7;              // 32 m-tiles
  int n0 = (wg & 15) << 6;              // 16 n-tiles

  int r0s = t >> 2;
  int r1s = r0s + 64;
  int dst0 = (t & 3) * 8;
  int src0 = ((t & 3) ^ ((r0s & 3) ^ ((r0s >> 2) & 1))) * 8;

  const u16* Ap0 = &A [(size_t)(m0 + r0s) * 1024 + src0];
  const u16* Ap1 = &A [(size_t)(m0 + r1s) * 1024 + src0];
  const u16* Bp  = &Bt[(size_t)(n0 + r0s) * 1024 + src0];   // B rows 0..63

  int csw = (quad ^ ((mrow & 3) ^ ((mrow >> 2) & 1))) * 8;

  f32x4 acc[4][2];
  #pragma unroll
  for (int ms = 0; ms < 4; ms++)
    #pragma unroll
    for (int ns = 0; ns < 2; ns++) acc[ms][ns] = (f32x4){0.f, 0.f, 0.f, 0.f};

  // prologue: stage tiles 0 and 1
  GLD_LDS(Ap0,      &Al[0][r0s][dst0]);
  GLD_LDS(Ap1,      &Al[0][r1s][dst0]);
  GLD_LDS(Bp,       &Bl[0][r0s][dst0]);
  CFENCE();
  GLD_LDS(Ap0 + 32, &Al[1][r0s][dst0]);
  GLD_LDS(Ap1 + 32, &Al[1][r1s][dst0]);
  GLD_LDS(Bp  + 32, &Bl[1][r0s][dst0]);

  int cur = 0, pf = 2;
  for (int kt = 0; kt < 32; kt++){
    if (kt < 31) WAIT_VM(3); else WAIT_VM(0);
    __builtin_amdgcn_s_barrier();
    CFENCE();
    if (kt < 30){
      int K2 = (kt + 2) * 32;
      GLD_LDS(Ap0 + K2, &Al[pf][r0s][dst0]);
      GLD_LDS(Ap1 + K2, &Al[pf][r1s][dst0]);
      GLD_LDS(Bp  + K2, &Bl[pf][r0s][dst0]);
    }
    bf16x8 af[4], bfr[2];
    #pragma unroll
    for (int ms = 0; ms < 4; ms++)
      af[ms] = *(const bf16x8*)&Al[cur][wm * 64 + ms * 16 + mrow][csw];
    #pragma unroll
    for (int ns = 0; ns < 2; ns++)
      bfr[ns] = *(const bf16x8*)&Bl[cur][wn * 32 + ns * 16 + mrow][csw];
    #pragma unroll
    for (int ms = 0; ms < 4; ms++)
      #pragma unroll
      for (int ns = 0; ns < 2; ns++)
        acc[ms][ns] = __builtin_amdgcn_mfma_f32_16x16x32_bf16(af[ms], bfr[ns], acc[ms][ns], 0, 0, 0);
    cur = (cur == 2) ? 0 : cur + 1;
    pf  = (pf  == 2) ? 0 : pf  + 1;
  }

  __syncthreads();
  // repack fp32 [ls=m-local 0..127][ld=n-local 0..63], chunk XOR ph=(ld>>2)^(ls&15)
  #pragma unroll
  for (int ms = 0; ms < 4; ms++){
    #pragma unroll
    for (int ns = 0; ns < 2; ns++){
      int ld  = wn * 32 + ns * 16 + mrow;
      int lsb = wm * 64 + ms * 16 + quad * 4;
      #pragma unroll
      for (int r = 0; r < 4; r++){
        int ls = lsb + r;
        int ph = (ld >> 2) ^ (ls & 15);
        *(float*)(smem + ls * 256 + ph * 16 + (ld & 3) * 4) = acc[ms][ns][r];
      }
    }
  }
  __syncthreads();
  #pragma unroll
  for (int j = 0; j < 8; j++){
    int row = w * 32 + j * 4 + (lane >> 4);
    int c   = lane & 15;
    int ph  = c ^ (row & 15);
    float4 v = *(float4*)(smem + row * 256 + ph * 16);
    float4 bb = *(const float4*)&bias[n0 + c * 4];
    v.x += bb.x; v.y += bb.y; v.z += bb.z; v.w += bb.w;
    *(float4*)&C[(size_t)(m0 + row) * 1024 + n0 + c * 4] = v;
  }
}

// ---------------- Flash attention: software-pipelined, 4 waves x 32 q-rows --------
// R13 known-good loop (47.8 us): 4 LDS buffers, 2-deep pipeline, WAIT_VM(6)
// steady state, in-register P, ones x P denominator.
// SINGLE CHANGE THIS ROUND: coalesced epilogue. Repack O through the dead Kl
// region (Kl[0..1], 16 KB; last ds_reads at kt=27/28 lookaheads; all waves past
// the unconditional kt=31 barrier; outstanding GLDs = 0 after kt=30's full
// drain), then store contiguous 128B rows (8 lines/wave-store) instead of 16
// scattered 8B stores/thread at 2KB stride (64 lines/wave-store).
// Mapping verified: (quad>>1)*8+(quad&1)*4 == quad*4; write/read swizzle is the
// same involution ph = chunk ^ (lq&7).
__global__ __launch_bounds__(256) void k_attn(const u16* q,
                                              const u16* __restrict__ k,
                                              const u16* __restrict__ vt,
                                              u16* nv){
  __shared__ u16 Kl[4][64][64];
  __shared__ u16 Vl[4][64][64];
  int t = threadIdx.x, lane = t & 63, w = t >> 6;    // w in 0..3
  int mrow = lane & 15, quad = lane >> 4;
  int id = blockIdx.x;
  int wg = (id & 7) * 64 + (id >> 3);                // 512 wgs, 64/XCD chunk
  int s0 = (wg & 15) * 128;
  int bh = wg >> 4; int b = bh >> 4, hh = bh & 15;

  const u16* qrow0 = q + (size_t)((b * SEQ + s0 + w * 32 + mrow) * NH + hh) * DH;
  const u16* qrow1 = qrow0 + 16 * NH * DH;
  bf16x8 bq[2][2];
  bq[0][0] = *(const bf16x8*)(qrow0 + quad * 8);
  bq[0][1] = *(const bf16x8*)(qrow0 + 32 + quad * 8);
  bq[1][0] = *(const bf16x8*)(qrow1 + quad * 8);
  bq[1][1] = *(const bf16x8*)(qrow1 + 32 + quad * 8);

  int rw  = t >> 3;                                  // 0..31
  int fst = (rw & 3) | (((t >> 6) & 1) << 2);
  int lc  = (t & 7) ^ fst;                           // logical chunk to fetch
  const u16* kp = k  + ((size_t)b * SEQ + rw) * (NH * DH) + hh * DH + lc * 8;
  const u16* vp = vt + ((size_t)bh * DH + rw) * SEQ + lc * 8;

  int row0 = ((mrow >> 2) << 3) | (mrow & 3);                       // pi_0(mrow)
  int cK = (quad ^ ((mrow & 3) | (((mrow >> 2) & 1) << 2))) << 4;   // byte of a0 chunk
  int cV = (quad ^ ((mrow & 3) | (((mrow >> 3) & 1) << 2))) << 4;

  f32x4 o[2][4];
  #pragma unroll
  for (int qg = 0; qg < 2; qg++)
    #pragma unroll
    for (int g = 0; g < 4; g++) o[qg][g] = (f32x4){0.f, 0.f, 0.f, 0.f};
  f32x4 accl[2];
  accl[0] = (f32x4){0.f, 0.f, 0.f, 0.f};
  accl[1] = (f32x4){0.f, 0.f, 0.f, 0.f};
  bf16x8 onesf;
  #pragma unroll
  for (int j = 0; j < 8; j++) onesf[j] = (short)0x3F80;             // bf16 1.0

#define STAGE_KV(BUF) do{ \
    u16* dK = (u16*)Kl[BUF]; u16* dV = (u16*)Vl[BUF]; \
    GLD_LDS(kp,                dK + (t << 3)); \
    GLD_LDS(kp + 32 * NH * DH, dK + 2048 + (t << 3)); \
    CFENCE(); \
    GLD_LDS(vp,                dV + (t << 3)); \
    GLD_LDS(vp + 32 * SEQ,     dV + 2048 + (t << 3)); \
    kp += 64 * NH * DH; vp += 64; \
    CFENCE(); \
  }while(0)

#define QKT4(KB, S0, S1) do{ \
    const char* Kb_ = (const char*)(KB); \
    _Pragma("unroll") \
    for (int g = 0; g < 4; g++){ \
      int rg = row0 + ((g & 1) << 2) + ((g >> 1) << 5); \
      const char* rp = Kb_ + rg * 128; \
      bf16x8 a0 = *(const bf16x8*)(rp + cK); \
      bf16x8 a1 = *(const bf16x8*)(rp + (cK ^ 64)); \
      f32x4 z0 = (f32x4){0.f, 0.f, 0.f, 0.f}; \
      f32x4 z1 = (f32x4){0.f, 0.f, 0.f, 0.f}; \
      z0 = __builtin_amdgcn_mfma_f32_16x16x32_bf16(a0, bq[0][0], z0, 0, 0, 0); \
      z1 = __builtin_amdgcn_mfma_f32_16x16x32_bf16(a0, bq[1][0], z1, 0, 0, 0); \
      z0 = __builtin_amdgcn_mfma_f32_16x16x32_bf16(a1, bq[0][1], z0, 0, 0, 0); \
      z1 = __builtin_amdgcn_mfma_f32_16x16x32_bf16(a1, bq[1][1], z1, 0, 0, 0); \
      (S0)[g] = z0; (S1)[g] = z1; \
    } \
  }while(0)

  // prologue: stage tiles 0,1,2 into buffers 0,1,2
  STAGE_KV(0);
  STAGE_KV(1);
  STAGE_KV(2);
  WAIT_VM(8);                     // own tile-0 loads landed
  __builtin_amdgcn_s_barrier();   // everyone's tile-0 loads landed
  CFENCE();

  f32x4 sc0[4], sc1[4], sn0[4], sn1[4];
  __builtin_amdgcn_s_setprio(1);
  QKT4(Kl[0], sc0, sc1);          // S^T for tile 0
  __builtin_amdgcn_s_setprio(0);

  for (int kt = 0; kt < 32; kt++){
    int cb = kt & 3;
    if (kt < 30) WAIT_VM(6);                      // drains V[kt] + K[kt+1] exactly
    else if (kt == 30) WAIT_VM(0);                // tail: drain everything
    __builtin_amdgcn_s_barrier();                 // broadcast across waves
    CFENCE();
    if (kt <= 28) STAGE_KV((kt + 3) & 3);         // overwrites tile kt-1 (reads pre-barrier)

    // QK^T for tile kt+1 — MFMAs overlap the exp/pack VALU below
    if (kt < 31){
      __builtin_amdgcn_s_setprio(1);
      QKT4(Kl[(kt + 1) & 3], sn0, sn1);
      __builtin_amdgcn_s_setprio(0);
    }

    // exp2 + pack for tile kt (from sc*, computed last iteration)
    bf16x8 pb[2][2];
    #pragma unroll
    for (int qg = 0; qg < 2; qg++){
      u32 wd[8];
      #pragma unroll
      for (int g = 0; g < 4; g++){
        f32x4 sg = qg ? sc1[g] : sc0[g];
        float e0 = __builtin_amdgcn_exp2f(sg[0]);
        float e1 = __builtin_amdgcn_exp2f(sg[1]);
        float e2 = __builtin_amdgcn_exp2f(sg[2]);
        float e3 = __builtin_amdgcn_exp2f(sg[3]);
        wd[g * 2]     = cvt_pk_bf16(e0, e1);
        wd[g * 2 + 1] = cvt_pk_bf16(e2, e3);
      }
      union { u32 u[4]; bf16x8 v; } U0, U1;
      U0.u[0] = wd[0]; U0.u[1] = wd[1]; U0.u[2] = wd[2]; U0.u[3] = wd[3];
      U1.u[0] = wd[4]; U1.u[1] = wd[5]; U1.u[2] = wd[6]; U1.u[3] = wd[7];
      pb[qg][0] = U0.v; pb[qg][1] = U1.v;
    }

    __builtin_amdgcn_s_setprio(1);
    // denominator on the matrix pipe
    #pragma unroll
    for (int qg = 0; qg < 2; qg++){
      accl[qg] = __builtin_amdgcn_mfma_f32_16x16x32_bf16(onesf, pb[qg][0], accl[qg], 0, 0, 0);
      accl[qg] = __builtin_amdgcn_mfma_f32_16x16x32_bf16(onesf, pb[qg][1], accl[qg], 0, 0, 0);
    }
    // O^T[e][q] += V^T[e][kk] . P[kk][q] ; V fragment shared by both q-groups
    const char* Vb = (const char*)Vl[cb];
    #pragma unroll
    for (int ge = 0; ge < 4; ge++){
      const char* rp = Vb + (ge * 16 + mrow) * 128;
      bf16x8 v0 = *(const bf16x8*)(rp + cV);
      bf16x8 v1 = *(const bf16x8*)(rp + (cV ^ 64));
      o[0][ge] = __builtin_amdgcn_mfma_f32_16x16x32_bf16(v0, pb[0][0], o[0][ge], 0, 0, 0);
      o[1][ge] = __builtin_amdgcn_mfma_f32_16x16x32_bf16(v0, pb[1][0], o[1][ge], 0, 0, 0);
      o[0][ge] = __builtin_amdgcn_mfma_f32_16x16x32_bf16(v1, pb[0][1], o[0][ge], 0, 0, 0);
      o[1][ge] = __builtin_amdgcn_mfma_f32_16x16x32_bf16(v1, pb[1][1], o[1][ge], 0, 0, 0);
    }
    __builtin_amdgcn_s_setprio(0);

    if (kt < 31){   // roll pipeline registers
      #pragma unroll
      for (int g = 0; g < 4; g++){ sc0[g] = sn0[g]; sc1[g] = sn1[g]; }
    }
  }

  // ---- epilogue: LDS repack into dead Kl region + coalesced uint4 stores ----
  // write: q-row lq = w*32 + qg*16 + mrow; logical 16B chunk c16 = ge*2+(quad>>1),
  // phys chunk = c16 ^ (lq&7), slot (quad&1)*8 (elements ge*16+quad*4..+3).
  // read: 8 lanes/row cover a full 128B row -> wave-store = 8 contiguous rows.
  {
    char* Ol = (char*)Kl;     // [128][64] bf16, chunk-XOR swizzled (16 KB)
    #pragma unroll
    for (int qg = 0; qg < 2; qg++){
      float rl = 1.0f / accl[qg][0];
      int lq = w * 32 + qg * 16 + mrow;
      #pragma unroll
      for (int ge = 0; ge < 4; ge++){
        int c16 = ge * 2 + (quad >> 1);
        int ph  = c16 ^ (lq & 7);
        uint2 pk = { cvt_pk_bf16(o[qg][ge][0] * rl, o[qg][ge][1] * rl),
                     cvt_pk_bf16(o[qg][ge][2] * rl, o[qg][ge][3] * rl) };
        *(uint2*)(Ol + lq * 128 + ph * 16 + (quad & 1) * 8) = pk;
      }
    }
    __syncthreads();
    #pragma unroll
    for (int j = 0; j < 4; j++){
      int lq = w * 32 + j * 8 + (lane >> 3);
      int c  = lane & 7;
      int ph = c ^ (lq & 7);
      uint4 v = *(uint4*)(Ol + lq * 128 + ph * 16);
      *(uint4*)&nv[(size_t)((b * SEQ + s0 + lq) * NH + hh) * DH + c * 8] = v;
    }
  }
#undef STAGE_KV
#undef QKT4
}

extern "C" void kernel_launch(void* const* d_in, const int* in_sizes, int n_in,
                              void* d_out, int out_size, void* d_ws, size_t ws_size,
                              hipStream_t stream){
  const float* x   = (const float*)d_in[0];
  const float* nsc = (const float*)d_in[1];
  const float* wq  = (const float*)d_in[2];
  const float* wk  = (const float*)d_in[3];
  const float* wv  = (const float*)d_in[4];
  const float* wo  = (const float*)d_in[5];
  const float* bo  = (const float*)d_in[6];
  char* ws = (char*)d_ws;
  const size_t MB = (size_t)1 << 20;

  u16* qb  = (u16*)(ws);
  u16* kb  = (u16*)(ws + 8  * MB);
  u16* vtb = (u16*)(ws + 16 * MB);
  u16* h   = (u16*)d_out;
  u16* wT  = (u16*)((char*)d_out + 8 * MB);
  u16* wqT = wT;
  u16* wkT = wT + (1u << 20);
  u16* wvT = wT + (2u << 20);
  u16* woT = kb;

  k_rmsnorm<<<NROW, 256, 0, stream>>>(x, nsc, h);
  k_wtrans<<<dim3(16, 16, 3), 256, 0, stream>>>(wq, wk, wv, wT);
  k_gemm<<<dim3(768), 256, 0, stream>>>(h, wqT, wkT, wvT, qb, kb, vtb);
  k_attn<<<dim3(512), 256, 0, stream>>>(qb, kb, vtb, qb);
  k_wtrans<<<dim3(16, 16, 1), 256, 0, stream>>>(wo, wo, wo, woT);
  k_gemm_out<<<dim3(512), 256, 0, stream>>>(qb, woT, (float*)d_out, bo);
}

// Round 18
// 185.234 us; speedup vs baseline: 1.0009x; 1.0009x over previous
//
#include <hip/hip_runtime.h>

typedef unsigned short u16;
typedef unsigned int   u32;
typedef __attribute__((ext_vector_type(8))) short bf16x8;
typedef __attribute__((ext_vector_type(4))) float f32x4;

#define SEQ 2048
#define DIM 1024
#define NH  16
#define DH  64
#define NROW 4096

static __device__ __forceinline__ u16 f2bf(float f){
  u32 u; __builtin_memcpy(&u, &f, 4);
  u32 r = (u + 0x7fffu + ((u >> 16) & 1u)) >> 16;
  return (u16)r;
}
// round-half-up pack of two fp32 -> two bf16 in one u32 (low = a, high = b)
static __device__ __forceinline__ u32 pack2bf(float a, float b){
  u32 ua, ub; __builtin_memcpy(&ua, &a, 4); __builtin_memcpy(&ub, &b, 4);
  return ((ua + 0x8000u) >> 16) | ((ub + 0x8000u) & 0xFFFF0000u);
}
// single-instruction RNE pack (lo = a, hi = b)
static __device__ __forceinline__ u32 cvt_pk_bf16(float a, float b){
  u32 r;
  asm("v_cvt_pk_bf16_f32 %0, %1, %2" : "=v"(r) : "v"(a), "v"(b));
  return r;
}

#define GLD_LDS(gp, lp) \
  __builtin_amdgcn_global_load_lds( \
      (const __attribute__((address_space(1))) void*)(gp), \
      (__attribute__((address_space(3))) void*)(lp), 16, 0, 0)

// counted waitcnt with compiler memory fence (blocks ds_read/GLD motion across)
#define WAIT_VM(N) asm volatile("s_waitcnt vmcnt(" #N ")" ::: "memory")
#define CFENCE()   asm volatile("" ::: "memory")

// -------- Fused pre-pass: rmsnorm (blocks 0..4095) + QKV wtrans (4096..4863) ------
// ISOLATED EXPERIMENT THIS ROUND (from the R14 bundle; R16 proved the gemm_out
// retile alone trips the tripwire, so this tests k_pre's innocence).
// Block-uniform branch, disjoint outputs, uniform __syncthreads on both paths.
__global__ __launch_bounds__(256) void k_pre(const float* __restrict__ x,
                                             const float* __restrict__ sc,
                                             u16* __restrict__ h,
                                             const float* __restrict__ wq,
                                             const float* __restrict__ wk,
                                             const float* __restrict__ wv,
                                             u16* __restrict__ wT){
  __shared__ u16 tile[64][68];
  __shared__ float red[4];
  int t = threadIdx.x;
  if ((int)blockIdx.x < NROW){
    int row = blockIdx.x;
    float4 v = ((const float4*)(x + (size_t)row * DIM))[t];
    float ss = v.x*v.x + v.y*v.y + v.z*v.z + v.w*v.w;
    #pragma unroll
    for (int d = 32; d; d >>= 1) ss += __shfl_down(ss, d, 64);
    if ((t & 63) == 0) red[t >> 6] = ss;
    __syncthreads();
    float tot = red[0] + red[1] + red[2] + red[3];
    float rms = rsqrtf(tot * (1.0f / DIM) + 1e-6f);
    float4 s4 = ((const float4*)sc)[t];
    u16 ov[4];
    ov[0] = f2bf(v.x * rms * s4.x);
    ov[1] = f2bf(v.y * rms * s4.y);
    ov[2] = f2bf(v.z * rms * s4.z);
    ov[3] = f2bf(v.w * rms * s4.w);
    ((uint2*)(h + (size_t)row * DIM))[t] = *(uint2*)ov;
  } else {
    int idx = blockIdx.x - NROW;          // 0..767
    int z = idx >> 8, rem = idx & 255;
    int c0 = (rem & 15) * 64;             // n
    int r0 = (rem >> 4) * 64;             // k
    const float* in = (z == 0) ? wq : ((z == 1) ? wk : wv);
    u16* out = wT + (size_t)z * (1u << 20);
    #pragma unroll
    for (int i = 0; i < 4; i++){
      int id2 = t + 256 * i;
      int r = id2 >> 4, c4 = (id2 & 15) * 4;
      float4 v = *(const float4*)&in[(size_t)(r0 + r) * 1024 + c0 + c4];
      u16 pk[4] = {f2bf(v.x), f2bf(v.y), f2bf(v.z), f2bf(v.w)};
      *(uint2*)&tile[r][c4] = *(uint2*)pk;
    }
    __syncthreads();
    #pragma unroll
    for (int i = 0; i < 2; i++){
      int c = t + 256 * i;
      int n = c >> 3, koff = (c & 7) * 8;
      alignas(16) u16 vals[8];
      #pragma unroll
      for (int j = 0; j < 8; j++) vals[j] = tile[koff + j][n];
      *(uint4*)&out[(size_t)(c0 + n) * 1024 + r0 + koff] = *(uint4*)vals;
    }
  }
}

// ------- Weight transpose (wo only): fp32 K-major -> bf16 N-major [n][k] ----------
__global__ __launch_bounds__(256) void k_wtrans(const float* __restrict__ in0,
                                                const float* __restrict__ in1,
                                                const float* __restrict__ in2,
                                                u16* __restrict__ outT){
  __shared__ u16 tile[64][68];
  int t = threadIdx.x;
  int c0 = blockIdx.x * 64;   // n
  int r0 = blockIdx.y * 64;   // k
  int z = blockIdx.z;
  const float* in = (z == 0) ? in0 : ((z == 1) ? in1 : in2);
  u16* out = outT + (size_t)z * (1u << 20);
  #pragma unroll
  for (int i = 0; i < 4; i++){
    int idx = t + 256 * i;
    int r = idx >> 4, c4 = (idx & 15) * 4;
    float4 v = *(const float4*)&in[(size_t)(r0 + r) * 1024 + c0 + c4];
    u16 pk[4] = {f2bf(v.x), f2bf(v.y), f2bf(v.z), f2bf(v.w)};
    *(uint2*)&tile[r][c4] = *(uint2*)pk;
  }
  __syncthreads();
  #pragma unroll
  for (int i = 0; i < 2; i++){
    int c = t + 256 * i;
    int n = c >> 3, koff = (c & 7) * 8;
    alignas(16) u16 vals[8];
    #pragma unroll
    for (int j = 0; j < 8; j++) vals[j] = tile[koff + j][n];
    *(uint4*)&out[(size_t)(c0 + n) * 1024 + r0 + koff] = *(uint4*)vals;
  }
}

// ---------------- QKV GEMM: 128x128, triple-buffered counted-vmcnt, T2 swizzle ----
// (R13/R17 known-good, verbatim.)
__global__ __launch_bounds__(256) void k_gemm(const u16* __restrict__ A,
                                              const u16* __restrict__ B0,
                                              const u16* __restrict__ B1,
                                              const u16* __restrict__ B2,
                                              void* __restrict__ C0,
                                              void* __restrict__ C1,
                                              void* __restrict__ C2){
  __shared__ __align__(16) char smem[49152];      // 3-buf staging; reused for repack
  u16 (*Al)[128][32] = (u16 (*)[128][32])smem;
  u16 (*Bl)[128][32] = (u16 (*)[128][32])(smem + 24576);
  int t = threadIdx.x, lane = t & 63, w = t >> 6;
  int wm = w & 1, wn = w >> 1;
  int mrow = lane & 15, quad = lane >> 4;

  int id = blockIdx.x;
  int wg = (id & 7) * 96 + (id >> 3);   // 768 wgs, 96/XCD chunk
  int z = wg >> 8;
  int rem = wg & 255;
  int m0 = (rem >> 3) << 7;   // m-minor within XCD chunk
  int n0 = (rem & 7) << 7;
  const u16* Bt = (z == 0) ? B0 : ((z == 1) ? B1 : B2);

  int r0s = t >> 2;                      // staged row (i=0); i=1 -> +64
  int r1s = r0s + 64;
  int dst0 = (t & 3) * 8;                // LDS linear chunk (u16 units)
  int src0 = ((t & 3) ^ ((r0s & 3) ^ ((r0s >> 2) & 1))) * 8;   // swizzled global chunk

  const u16* Ap0 = &A [(size_t)(m0 + r0s) * 1024 + src0];
  const u16* Ap1 = &A [(size_t)(m0 + r1s) * 1024 + src0];
  const u16* Bp0 = &Bt[(size_t)(n0 + r0s) * 1024 + src0];
  const u16* Bp1 = &Bt[(size_t)(n0 + r1s) * 1024 + src0];

  int csw = (quad ^ ((mrow & 3) ^ ((mrow >> 2) & 1))) * 8;

  f32x4 acc[4][4];
  #pragma unroll
  for (int ms = 0; ms < 4; ms++)
    #pragma unroll
    for (int ns = 0; ns < 4; ns++) acc[ms][ns] = (f32x4){0.f, 0.f, 0.f, 0.f};

  GLD_LDS(Ap0,      &Al[0][r0s][dst0]);
  GLD_LDS(Ap1,      &Al[0][r1s][dst0]);
  GLD_LDS(Bp0,      &Bl[0][r0s][dst0]);
  GLD_LDS(Bp1,      &Bl[0][r1s][dst0]);
  CFENCE();
  GLD_LDS(Ap0 + 32, &Al[1][r0s][dst0]);
  GLD_LDS(Ap1 + 32, &Al[1][r1s][dst0]);
  GLD_LDS(Bp0 + 32, &Bl[1][r0s][dst0]);
  GLD_LDS(Bp1 + 32, &Bl[1][r1s][dst0]);

  int cur = 0, pf = 2;
  for (int kt = 0; kt < 32; kt++){
    if (kt < 31) WAIT_VM(4); else WAIT_VM(0);
    __builtin_amdgcn_s_barrier();
    CFENCE();
    if (kt < 30){
      int K2 = (kt + 2) * 32;
      GLD_LDS(Ap0 + K2, &Al[pf][r0s][dst0]);
      GLD_LDS(Ap1 + K2, &Al[pf][r1s][dst0]);
      GLD_LDS(Bp0 + K2, &Bl[pf][r0s][dst0]);
      GLD_LDS(Bp1 + K2, &Bl[pf][r1s][dst0]);
    }
    bf16x8 af[4], bfr[4];
    #pragma unroll
    for (int ms = 0; ms < 4; ms++)
      af[ms] = *(const bf16x8*)&Al[cur][wm * 64 + ms * 16 + mrow][csw];
    #pragma unroll
    for (int ns = 0; ns < 4; ns++)
      bfr[ns] = *(const bf16x8*)&Bl[cur][wn * 64 + ns * 16 + mrow][csw];
    #pragma unroll
    for (int ms = 0; ms < 4; ms++)
      #pragma unroll
      for (int ns = 0; ns < 4; ns++)
        acc[ms][ns] = __builtin_amdgcn_mfma_f32_16x16x32_bf16(af[ms], bfr[ns], acc[ms][ns], 0, 0, 0);
    cur = (cur == 2) ? 0 : cur + 1;
    pf  = (pf  == 2) ? 0 : pf  + 1;
  }

  float qscale = (z == 0) ? 0.180336880111112f : 1.0f;   // 0.125*log2e folded into Q

  __syncthreads();
  if (z == 2){
    #pragma unroll
    for (int ms = 0; ms < 4; ms++){
      #pragma unroll
      for (int ns = 0; ns < 4; ns++){
        int le = wn * 64 + ns * 16 + mrow;
        int ls = wm * 64 + ms * 16 + quad * 4;
        int ph = (ls >> 3) ^ (le & 7);
        uint2 pk = { pack2bf(acc[ms][ns][0], acc[ms][ns][1]),
                     pack2bf(acc[ms][ns][2], acc[ms][ns][3]) };
        *(uint2*)(smem + le * 256 + ph * 16 + (ls & 7) * 2) = pk;
      }
    }
    __syncthreads();
    int bidx = m0 >> 11, sl0 = m0 & 2047;
    u16* Cb = (u16*)C2;
    #pragma unroll
    for (int j = 0; j < 8; j++){
      int le = w * 32 + j * 4 + (lane >> 4);
      int c  = lane & 15;
      int ph = c ^ (le & 7);
      int hh2 = (n0 + le) >> 6, e = (n0 + le) & 63;
      uint4 v = *(uint4*)(smem + le * 256 + ph * 16);
      *(uint4*)&Cb[(size_t)((bidx * NH + hh2) * DH + e) * SEQ + sl0 + c * 8] = v;
    }
  } else {
    #pragma unroll
    for (int ms = 0; ms < 4; ms++){
      #pragma unroll
      for (int ns = 0; ns < 4; ns++){
        int ld  = wn * 64 + ns * 16 + mrow;
        int lsb = wm * 64 + ms * 16 + quad * 4;
        #pragma unroll
        for (int r = 0; r < 4; r++){
          int ls = lsb + r;
          int ph = (ld >> 3) ^ (ls & 7);
          *(u16*)(smem + ls * 256 + ph * 16 + (ld & 7) * 2) = f2bf(acc[ms][ns][r] * qscale);
        }
      }
    }
    __syncthreads();
    u16* Cb = (u16*)((z == 0) ? C0 : C1);
    #pragma unroll
    for (int j = 0; j < 8; j++){
      int row = w * 32 + j * 4 + (lane >> 4);
      int c   = lane & 15;
      int ph  = c ^ (row & 7);
      uint4 v = *(uint4*)(smem + row * 256 + ph * 16);
      *(uint4*)&Cb[(size_t)(m0 + row) * 1024 + n0 + c * 8] = v;
    }
  }
}

// ---------------- Out-proj GEMM: 128m x 64n tiles, grid 512 (R13 verbatim) --------
// R16 identified the 64x64/grid-1024 retile as a timing-sensitive racer — this
// version is the verified one and is frozen.
__global__ __launch_bounds__(256) void k_gemm_out(const u16* __restrict__ A,
                                                  const u16* __restrict__ Bt,
                                                  float* __restrict__ C,
                                                  const float* __restrict__ bias){
  __shared__ __align__(16) char smem[36864];      // A 24KB + B 12KB staging; repack 32KB
  u16 (*Al)[128][32] = (u16 (*)[128][32])smem;
  u16 (*Bl)[ 64][32] = (u16 (*)[ 64][32])(smem + 24576);
  int t = threadIdx.x, lane = t & 63, w = t >> 6;
  int wm = w & 1, wn = w >> 1;
  int mrow = lane & 15, quad = lane >> 4;

  int id = blockIdx.x;
  int wg = (id & 7) * 64 + (id >> 3);   // 512 wgs, 64/XCD chunk
  int m0 = (wg >> 4) << 7;              // 32 m-tiles
  int n0 = (wg & 15) << 6;              // 16 n-tiles

  int r0s = t >> 2;
  int r1s = r0s + 64;
  int dst0 = (t & 3) * 8;
  int src0 = ((t & 3) ^ ((r0s & 3) ^ ((r0s >> 2) & 1))) * 8;

  const u16* Ap0 = &A [(size_t)(m0 + r0s) * 1024 + src0];
  const u16* Ap1 = &A [(size_t)(m0 + r1s) * 1024 + src0];
  const u16* Bp  = &Bt[(size_t)(n0 + r0s) * 1024 + src0];   // B rows 0..63

  int csw = (quad ^ ((mrow & 3) ^ ((mrow >> 2) & 1))) * 8;

  f32x4 acc[4][2];
  #pragma unroll
  for (int ms = 0; ms < 4; ms++)
    #pragma unroll
    for (int ns = 0; ns < 2; ns++) acc[ms][ns] = (f32x4){0.f, 0.f, 0.f, 0.f};

  // prologue: stage tiles 0 and 1
  GLD_LDS(Ap0,      &Al[0][r0s][dst0]);
  GLD_LDS(Ap1,      &Al[0][r1s][dst0]);
  GLD_LDS(Bp,       &Bl[0][r0s][dst0]);
  CFENCE();
  GLD_LDS(Ap0 + 32, &Al[1][r0s][dst0]);
  GLD_LDS(Ap1 + 32, &Al[1][r1s][dst0]);
  GLD_LDS(Bp  + 32, &Bl[1][r0s][dst0]);

  int cur = 0, pf = 2;
  for (int kt = 0; kt < 32; kt++){
    if (kt < 31) WAIT_VM(3); else WAIT_VM(0);
    __builtin_amdgcn_s_barrier();
    CFENCE();
    if (kt < 30){
      int K2 = (kt + 2) * 32;
      GLD_LDS(Ap0 + K2, &Al[pf][r0s][dst0]);
      GLD_LDS(Ap1 + K2, &Al[pf][r1s][dst0]);
      GLD_LDS(Bp  + K2, &Bl[pf][r0s][dst0]);
    }
    bf16x8 af[4], bfr[2];
    #pragma unroll
    for (int ms = 0; ms < 4; ms++)
      af[ms] = *(const bf16x8*)&Al[cur][wm * 64 + ms * 16 + mrow][csw];
    #pragma unroll
    for (int ns = 0; ns < 2; ns++)
      bfr[ns] = *(const bf16x8*)&Bl[cur][wn * 32 + ns * 16 + mrow][csw];
    #pragma unroll
    for (int ms = 0; ms < 4; ms++)
      #pragma unroll
      for (int ns = 0; ns < 2; ns++)
        acc[ms][ns] = __builtin_amdgcn_mfma_f32_16x16x32_bf16(af[ms], bfr[ns], acc[ms][ns], 0, 0, 0);
    cur = (cur == 2) ? 0 : cur + 1;
    pf  = (pf  == 2) ? 0 : pf  + 1;
  }

  __syncthreads();
  // repack fp32 [ls=m-local 0..127][ld=n-local 0..63], chunk XOR ph=(ld>>2)^(ls&15)
  #pragma unroll
  for (int ms = 0; ms < 4; ms++){
    #pragma unroll
    for (int ns = 0; ns < 2; ns++){
      int ld  = wn * 32 + ns * 16 + mrow;
      int lsb = wm * 64 + ms * 16 + quad * 4;
      #pragma unroll
      for (int r = 0; r < 4; r++){
        int ls = lsb + r;
        int ph = (ld >> 2) ^ (ls & 15);
        *(float*)(smem + ls * 256 + ph * 16 + (ld & 3) * 4) = acc[ms][ns][r];
      }
    }
  }
  __syncthreads();
  #pragma unroll
  for (int j = 0; j < 8; j++){
    int row = w * 32 + j * 4 + (lane >> 4);
    int c   = lane & 15;
    int ph  = c ^ (row & 15);
    float4 v = *(float4*)(smem + row * 256 + ph * 16);
    float4 bb = *(const float4*)&bias[n0 + c * 4];
    v.x += bb.x; v.y += bb.y; v.z += bb.z; v.w += bb.w;
    *(float4*)&C[(size_t)(m0 + row) * 1024 + n0 + c * 4] = v;
  }
}

// ---------------- Flash attention: software-pipelined, 4 waves x 32 q-rows --------
// R17 known-good verbatim (48.1 us): 4 LDS buffers, 2-deep pipeline, WAIT_VM(6)
// steady state, in-register P, ones x P denominator, coalesced LDS-repack
// epilogue through dead Kl region.
__global__ __launch_bounds__(256) void k_attn(const u16* q,
                                              const u16* __restrict__ k,
                                              const u16* __restrict__ vt,
                                              u16* nv){
  __shared__ u16 Kl[4][64][64];
  __shared__ u16 Vl[4][64][64];
  int t = threadIdx.x, lane = t & 63, w = t >> 6;    // w in 0..3
  int mrow = lane & 15, quad = lane >> 4;
  int id = blockIdx.x;
  int wg = (id & 7) * 64 + (id >> 3);                // 512 wgs, 64/XCD chunk
  int s0 = (wg & 15) * 128;
  int bh = wg >> 4; int b = bh >> 4, hh = bh & 15;

  const u16* qrow0 = q + (size_t)((b * SEQ + s0 + w * 32 + mrow) * NH + hh) * DH;
  const u16* qrow1 = qrow0 + 16 * NH * DH;
  bf16x8 bq[2][2];
  bq[0][0] = *(const bf16x8*)(qrow0 + quad * 8);
  bq[0][1] = *(const bf16x8*)(qrow0 + 32 + quad * 8);
  bq[1][0] = *(const bf16x8*)(qrow1 + quad * 8);
  bq[1][1] = *(const bf16x8*)(qrow1 + 32 + quad * 8);

  int rw  = t >> 3;                                  // 0..31
  int fst = (rw & 3) | (((t >> 6) & 1) << 2);
  int lc  = (t & 7) ^ fst;                           // logical chunk to fetch
  const u16* kp = k  + ((size_t)b * SEQ + rw) * (NH * DH) + hh * DH + lc * 8;
  const u16* vp = vt + ((size_t)bh * DH + rw) * SEQ + lc * 8;

  int row0 = ((mrow >> 2) << 3) | (mrow & 3);                       // pi_0(mrow)
  int cK = (quad ^ ((mrow & 3) | (((mrow >> 2) & 1) << 2))) << 4;   // byte of a0 chunk
  int cV = (quad ^ ((mrow & 3) | (((mrow >> 3) & 1) << 2))) << 4;

  f32x4 o[2][4];
  #pragma unroll
  for (int qg = 0; qg < 2; qg++)
    #pragma unroll
    for (int g = 0; g < 4; g++) o[qg][g] = (f32x4){0.f, 0.f, 0.f, 0.f};
  f32x4 accl[2];
  accl[0] = (f32x4){0.f, 0.f, 0.f, 0.f};
  accl[1] = (f32x4){0.f, 0.f, 0.f, 0.f};
  bf16x8 onesf;
  #pragma unroll
  for (int j = 0; j < 8; j++) onesf[j] = (short)0x3F80;             // bf16 1.0

#define STAGE_KV(BUF) do{ \
    u16* dK = (u16*)Kl[BUF]; u16* dV = (u16*)Vl[BUF]; \
    GLD_LDS(kp,                dK + (t << 3)); \
    GLD_LDS(kp + 32 * NH * DH, dK + 2048 + (t << 3)); \
    CFENCE(); \
    GLD_LDS(vp,                dV + (t << 3)); \
    GLD_LDS(vp + 32 * SEQ,     dV + 2048 + (t << 3)); \
    kp += 64 * NH * DH; vp += 64; \
    CFENCE(); \
  }while(0)

#define QKT4(KB, S0, S1) do{ \
    const char* Kb_ = (const char*)(KB); \
    _Pragma("unroll") \
    for (int g = 0; g < 4; g++){ \
      int rg = row0 + ((g & 1) << 2) + ((g >> 1) << 5); \
      const char* rp = Kb_ + rg * 128; \
      bf16x8 a0 = *(const bf16x8*)(rp + cK); \
      bf16x8 a1 = *(const bf16x8*)(rp + (cK ^ 64)); \
      f32x4 z0 = (f32x4){0.f, 0.f, 0.f, 0.f}; \
      f32x4 z1 = (f32x4){0.f, 0.f, 0.f, 0.f}; \
      z0 = __builtin_amdgcn_mfma_f32_16x16x32_bf16(a0, bq[0][0], z0, 0, 0, 0); \
      z1 = __builtin_amdgcn_mfma_f32_16x16x32_bf16(a0, bq[1][0], z1, 0, 0, 0); \
      z0 = __builtin_amdgcn_mfma_f32_16x16x32_bf16(a1, bq[0][1], z0, 0, 0, 0); \
      z1 = __builtin_amdgcn_mfma_f32_16x16x32_bf16(a1, bq[1][1], z1, 0, 0, 0); \
      (S0)[g] = z0; (S1)[g] = z1; \
    } \
  }while(0)

  // prologue: stage tiles 0,1,2 into buffers 0,1,2
  STAGE_KV(0);
  STAGE_KV(1);
  STAGE_KV(2);
  WAIT_VM(8);                     // own tile-0 loads landed
  __builtin_amdgcn_s_barrier();   // everyone's tile-0 loads landed
  CFENCE();

  f32x4 sc0[4], sc1[4], sn0[4], sn1[4];
  __builtin_amdgcn_s_setprio(1);
  QKT4(Kl[0], sc0, sc1);          // S^T for tile 0
  __builtin_amdgcn_s_setprio(0);

  for (int kt = 0; kt < 32; kt++){
    int cb = kt & 3;
    if (kt < 30) WAIT_VM(6);                      // drains V[kt] + K[kt+1] exactly
    else if (kt == 30) WAIT_VM(0);                // tail: drain everything
    __builtin_amdgcn_s_barrier();                 // broadcast across waves
    CFENCE();
    if (kt <= 28) STAGE_KV((kt + 3) & 3);         // overwrites tile kt-1 (reads pre-barrier)

    // QK^T for tile kt+1 — MFMAs overlap the exp/pack VALU below
    if (kt < 31){
      __builtin_amdgcn_s_setprio(1);
      QKT4(Kl[(kt + 1) & 3], sn0, sn1);
      __builtin_amdgcn_s_setprio(0);
    }

    // exp2 + pack for tile kt (from sc*, computed last iteration)
    bf16x8 pb[2][2];
    #pragma unroll
    for (int qg = 0; qg < 2; qg++){
      u32 wd[8];
      #pragma unroll
      for (int g = 0; g < 4; g++){
        f32x4 sg = qg ? sc1[g] : sc0[g];
        float e0 = __builtin_amdgcn_exp2f(sg[0]);
        float e1 = __builtin_amdgcn_exp2f(sg[1]);
        float e2 = __builtin_amdgcn_exp2f(sg[2]);
        float e3 = __builtin_amdgcn_exp2f(sg[3]);
        wd[g * 2]     = cvt_pk_bf16(e0, e1);
        wd[g * 2 + 1] = cvt_pk_bf16(e2, e3);
      }
      union { u32 u[4]; bf16x8 v; } U0, U1;
      U0.u[0] = wd[0]; U0.u[1] = wd[1]; U0.u[2] = wd[2]; U0.u[3] = wd[3];
      U1.u[0] = wd[4]; U1.u[1] = wd[5]; U1.u[2] = wd[6]; U1.u[3] = wd[7];
      pb[qg][0] = U0.v; pb[qg][1] = U1.v;
    }

    __builtin_amdgcn_s_setprio(1);
    // denominator on the matrix pipe
    #pragma unroll
    for (int qg = 0; qg < 2; qg++){
      accl[qg] = __builtin_amdgcn_mfma_f32_16x16x32_bf16(onesf, pb[qg][0], accl[qg], 0, 0, 0);
      accl[qg] = __builtin_amdgcn_mfma_f32_16x16x32_bf16(onesf, pb[qg][1], accl[qg], 0, 0, 0);
    }
    // O^T[e][q] += V^T[e][kk] . P[kk][q] ; V fragment shared by both q-groups
    const char* Vb = (const char*)Vl[cb];
    #pragma unroll
    for (int ge = 0; ge < 4; ge++){
      const char* rp = Vb + (ge * 16 + mrow) * 128;
      bf16x8 v0 = *(const bf16x8*)(rp + cV);
      bf16x8 v1 = *(const bf16x8*)(rp + (cV ^ 64));
      o[0][ge] = __builtin_amdgcn_mfma_f32_16x16x32_bf16(v0, pb[0][0], o[0][ge], 0, 0, 0);
      o[1][ge] = __builtin_amdgcn_mfma_f32_16x16x32_bf16(v0, pb[1][0], o[1][ge], 0, 0, 0);
      o[0][ge] = __builtin_amdgcn_mfma_f32_16x16x32_bf16(v1, pb[0][1], o[0][ge], 0, 0, 0);
      o[1][ge] = __builtin_amdgcn_mfma_f32_16x16x32_bf16(v1, pb[1][1], o[1][ge], 0, 0, 0);
    }
    __builtin_amdgcn_s_setprio(0);

    if (kt < 31){   // roll pipeline registers
      #pragma unroll
      for (int g = 0; g < 4; g++){ sc0[g] = sn0[g]; sc1[g] = sn1[g]; }
    }
  }

  // ---- epilogue: LDS repack into dead Kl region + coalesced uint4 stores ----
  {
    char* Ol = (char*)Kl;     // [128][64] bf16, chunk-XOR swizzled (16 KB)
    #pragma unroll
    for (int qg = 0; qg < 2; qg++){
      float rl = 1.0f / accl[qg][0];
      int lq = w * 32 + qg * 16 + mrow;
      #pragma unroll
      for (int ge = 0; ge < 4; ge++){
        int c16 = ge * 2 + (quad >> 1);
        int ph  = c16 ^ (lq & 7);
        uint2 pk = { cvt_pk_bf16(o[qg][ge][0] * rl, o[qg][ge][1] * rl),
                     cvt_pk_bf16(o[qg][ge][2] * rl, o[qg][ge][3] * rl) };
        *(uint2*)(Ol + lq * 128 + ph * 16 + (quad & 1) * 8) = pk;
      }
    }
    __syncthreads();
    #pragma unroll
    for (int j = 0; j < 4; j++){
      int lq = w * 32 + j * 8 + (lane >> 3);
      int c  = lane & 7;
      int ph = c ^ (lq & 7);
      uint4 v = *(uint4*)(Ol + lq * 128 + ph * 16);
      *(uint4*)&nv[(size_t)((b * SEQ + s0 + lq) * NH + hh) * DH + c * 8] = v;
    }
  }
#undef STAGE_KV
#undef QKT4
}

extern "C" void kernel_launch(void* const* d_in, const int* in_sizes, int n_in,
                              void* d_out, int out_size, void* d_ws, size_t ws_size,
                              hipStream_t stream){
  const float* x   = (const float*)d_in[0];
  const float* nsc = (const float*)d_in[1];
  const float* wq  = (const float*)d_in[2];
  const float* wk  = (const float*)d_in[3];
  const float* wv  = (const float*)d_in[4];
  const float* wo  = (const float*)d_in[5];
  const float* bo  = (const float*)d_in[6];
  char* ws = (char*)d_ws;
  const size_t MB = (size_t)1 << 20;

  u16* qb  = (u16*)(ws);
  u16* kb  = (u16*)(ws + 8  * MB);
  u16* vtb = (u16*)(ws + 16 * MB);
  u16* h   = (u16*)d_out;
  u16* wT  = (u16*)((char*)d_out + 8 * MB);
  u16* wqT = wT;
  u16* wkT = wT + (1u << 20);
  u16* wvT = wT + (2u << 20);
  u16* woT = kb;

  k_pre<<<dim3(NROW + 768), 256, 0, stream>>>(x, nsc, h, wq, wk, wv, wT);
  k_gemm<<<dim3(768), 256, 0, stream>>>(h, wqT, wkT, wvT, qb, kb, vtb);
  k_attn<<<dim3(512), 256, 0, stream>>>(qb, kb, vtb, qb);
  k_wtrans<<<dim3(16, 16, 1), 256, 0, stream>>>(wo, wo, wo, woT);
  k_gemm_out<<<dim3(512), 256, 0, stream>>>(qb, woT, (float*)d_out, bo);
}